// Round 4
// baseline (406719.531 us; speedup 1.0000x reference)
//
#include <hip/hip_runtime.h>
#include <hip/hip_bf16.h>
#include <stdint.h>
#include <stddef.h>

// tidigitsRNNPT: Elman RNN (B=128, SEQ=254, FEAT=39, HID=1024) -> FC1(260096->100)+ReLU -> FC2(100->10) -> log_softmax
//
// R3: XCD-local scan exchange. R2 post-mortem: sentinel memset made every first
// poll an HBM cold miss (FETCH 76->196MB) -> regressed. Root cause of the whole
// scan cost is exchange-medium LATENCY. Fix: batch-group teams are formed from
// blocks PHYSICALLY on the same XCD (runtime XCC_ID + per-XCD slot claim), so h
// exchange + flags go through the XCD-local L2 via sc0 (bypass L1, meet at L2)
// -- ~4x lower latency than IF, zero cross-XCD coherence requirements.
// Placement is guaranteed correctness-safe: 96KB LDS/block forces 1 block/CU,
// grid=256=CU count => exactly 32 blocks/XCD (pigeonhole); teams use slots 0-15,
// rest exit. Poll caps bound any anomaly to a wrong answer, never a hang.

typedef unsigned short u16;
typedef unsigned int u32;
typedef __attribute__((ext_vector_type(2))) unsigned int u32x2;
typedef __attribute__((ext_vector_type(4))) float f32x4;
typedef __attribute__((ext_vector_type(4))) unsigned short u16x4;
typedef __attribute__((ext_vector_type(8))) short short8;

#define SEQ   254
#define BATCH 128
#define HID   1024
#define FEAT  39
#define FC1N  100
#define FC1P  112
#define NCLS  10

// ---- workspace layout ----
#define OFF_SYNC  ((size_t)0)                                      // cnt[8] + flags (16KB)
#define OFF_HS    ((size_t)(16 * 1024))                            // (SEQ+1)*128*1024 bf16 = 66.8MB
#define OFF_WHH   (OFF_HS + (size_t)(SEQ + 1) * BATCH * HID * 2)   // 2MB
#define OFF_XP    (OFF_WHH + (size_t)HID * HID * 2)                // 66.6MB
#define OFF_PART  (OFF_XP + (size_t)SEQ * BATCH * HID * 2)         // 14.6MB

__device__ inline u16 f2bf(float f){
  union { float f; unsigned u; } v; v.f = f;
  unsigned u = v.u;
  u += 0x7fffu + ((u >> 16) & 1u);
  return (u16)(u >> 16);
}
__device__ inline float bf2f(u16 h){
  union { unsigned u; float f; } v; v.u = ((unsigned)h) << 16;
  return v.f;
}
__device__ inline float fast_tanh(float x){
  float e = __expf(2.0f * x);
  return 1.0f - 2.0f / (e + 1.0f);
}

// ---- XCD-local L2-coherent ops (sc0: bypass L1, meet at this XCD's L2) ----
__device__ inline short8 ld_l2x4(const u16* p){
  short8 r;
  asm volatile("global_load_dwordx4 %0, %1, off sc0" : "=v"(r) : "v"(p) : "memory");
  return r;
}
__device__ inline void st_l2x2(u16* p, u32x2 v){
  asm volatile("global_store_dwordx2 %0, %1, off sc0" :: "v"(p), "v"(v) : "memory");
}
__device__ inline void st_l2_i32(int* p, int v){
  asm volatile("global_store_dword %0, %1, off sc0" :: "v"(p), "v"(v) : "memory");
}
__device__ inline int ld_l2_i32(const int* p){
  int r;
  asm volatile("global_load_dword %0, %1, off sc0\n\ts_waitcnt vmcnt(0)"
               : "=v"(r) : "v"(p) : "memory");
  return r;
}

// ---------------- fp32 -> bf16 bulk convert ----------------
__global__ void cvt_f32_bf16_kernel(const float* __restrict__ in, u16* __restrict__ out, int n4){
  int i = blockIdx.x * blockDim.x + threadIdx.x;
  if (i < n4){
    f32x4 v = *(const f32x4*)(in + (size_t)i * 4);
    u16x4 o;
    o[0] = f2bf(v[0]); o[1] = f2bf(v[1]); o[2] = f2bf(v[2]); o[3] = f2bf(v[3]);
    *(u16x4*)(out + (size_t)i * 4) = o;
  }
}

// ---------------- xproj: [SEQ][BATCH][HID] bf16 (includes both biases) ----------------
__global__ __launch_bounds__(1024) void xproj_kernel(const float* __restrict__ x,
                                                     const float* __restrict__ W_ih,
                                                     const float* __restrict__ b_ih,
                                                     const float* __restrict__ b_hh,
                                                     u16* __restrict__ xp){
  const int s = blockIdx.x;
  __shared__ float xs[BATCH * (FEAT + 1)];
  for (int i = threadIdx.x; i < BATCH * FEAT; i += 1024){
    int b = i / FEAT, f = i - b * FEAT;
    xs[b * (FEAT + 1) + f] = x[((size_t)b * SEQ + s) * FEAT + f];
  }
  __syncthreads();
  const int h = threadIdx.x;
  float w[FEAT];
  #pragma unroll
  for (int f = 0; f < FEAT; ++f) w[f] = W_ih[h * FEAT + f];
  const float bias = b_ih[h] + b_hh[h];
  for (int b = 0; b < BATCH; ++b){
    float acc = bias;
    #pragma unroll
    for (int f = 0; f < FEAT; ++f) acc += xs[b * (FEAT + 1) + f] * w[f];
    xp[((size_t)s * BATCH + b) * HID + h] = f2bf(acc);
  }
}

// ---------------- XCD-local persistent RNN scan ----------------
// grid=256, 96KB LDS => 1 block/CU => exactly 32 blocks/XCD. Team = slots 0..15
// of one XCD, handles batch group bgrp=xcd (16 batches). Block owns 64 h-rows;
// wave owns 16 h-rows x full k. All h/flag traffic XCD-local via sc0.
__global__ __launch_bounds__(256, 1) void scan_kernel(const u16* __restrict__ whh,
                                                      const u16* __restrict__ xp,
                                                      u16* __restrict__ hs,
                                                      int* __restrict__ flags,
                                                      int* __restrict__ cnt){
  __shared__ int lds_force[24576];    // 96KB: hard cap 1 block/CU (pigeonhole)
  if (threadIdx.x == 0){
    int xcd;
    asm volatile("s_getreg_b32 %0, hwreg(HW_REG_XCC_ID)" : "=s"(xcd));
    xcd &= 7;
    lds_force[0] = xcd;
    lds_force[1] = atomicAdd(&cnt[xcd], 1);
  }
  __syncthreads();
  const int xcd  = lds_force[0];
  const int slot = lds_force[1];
  if (slot >= 16) return;            // 16 spare blocks/XCD exit

  const int wid  = threadIdx.x >> 6;
  const int lane = threadIdx.x & 63;
  const int lr = lane & 15;
  const int lg = lane >> 4;
  const int b_base = xcd * 16;

  // W_hh A-fragments, register-resident: wave covers h rows [slot*64+wid*16, +16)
  short8 breg[32];
  {
    const u16* wp = whh + (size_t)(slot * 64 + wid * 16 + lr) * HID + lg * 8;
    #pragma unroll
    for (int kk = 0; kk < 32; ++kk) breg[kk] = *(const short8*)(wp + kk * 32);
  }

  const size_t arow = (size_t)(b_base + lr) * HID + lg * 8;  // B-frag: h_t[b=lr][k]
  const int b_o = b_base + lr;                                // D col
  const int h_o = slot * 64 + wid * 16 + lg * 4;              // D rows (4 consec h)

  const int* fbase = flags + xcd * 16 * 16;                   // team flags, 64B stride

  for (int s = 0; s < SEQ; ++s){
    // wave 0 polls the 16 team flags (L2-local)
    if (wid == 0){
      const int* fp = fbase + lane * 16;
      int spins = 0;
      while (spins < (1 << 14)){
        int v = (lane < 16) ? ld_l2_i32(fp) : 0x7fffffff;
        if (__ballot(v < s) == 0ull) break;
        ++spins;
      }
    }
    __syncthreads();

    // load h_s fragments (XCD-local L2) + xproj init
    const u16* pa = hs + (size_t)s * (BATCH * HID) + arow;
    short8 a[32];
    #pragma unroll
    for (int kk = 0; kk < 32; ++kk) a[kk] = ld_l2x4(pa + kk * 32);
    u16x4 xv = *(const u16x4*)(xp + ((size_t)s * BATCH + b_o) * HID + h_o);

    asm volatile("s_waitcnt vmcnt(0)" ::: "memory");
    __builtin_amdgcn_sched_barrier(0);

    f32x4 acc0 = {0.f, 0.f, 0.f, 0.f}, acc1 = {0.f, 0.f, 0.f, 0.f};
    #pragma unroll
    for (int kk = 0; kk < 32; kk += 2){   // two interleaved dep chains
      acc0 = __builtin_amdgcn_mfma_f32_16x16x32_bf16(breg[kk],     a[kk],     acc0, 0, 0, 0);
      acc1 = __builtin_amdgcn_mfma_f32_16x16x32_bf16(breg[kk + 1], a[kk + 1], acc1, 0, 0, 0);
    }

    float v0 = fast_tanh(acc0[0] + acc1[0] + bf2f(xv[0]));
    float v1 = fast_tanh(acc0[1] + acc1[1] + bf2f(xv[1]));
    float v2 = fast_tanh(acc0[2] + acc1[2] + bf2f(xv[2]));
    float v3 = fast_tanh(acc0[3] + acc1[3] + bf2f(xv[3]));
    u32x2 d;
    d[0] = (u32)f2bf(v0) | ((u32)f2bf(v1) << 16);
    d[1] = (u32)f2bf(v2) | ((u32)f2bf(v3) << 16);
    st_l2x2(hs + (size_t)(s + 1) * (BATCH * HID) + (size_t)b_o * HID + h_o, d);

    asm volatile("s_waitcnt vmcnt(0)" ::: "memory");  // own stores in L2
    __syncthreads();                                   // whole block drained
    if (threadIdx.x == 0) st_l2_i32((int*)(fbase + slot * 16), s + 1);
  }
}

// ---------------- FC1 partials via MFMA ----------------
__global__ __launch_bounds__(256) void fc1_kernel(const u16* __restrict__ outs,
                                                  const float* __restrict__ W1,
                                                  float* __restrict__ part){
  const int s = blockIdx.x;
  const int wid  = threadIdx.x >> 6;
  const int lane = threadIdx.x & 63;
  const int lr = lane & 15;
  const int lg = lane >> 4;

  f32x4 acc[2][7];
  const f32x4 zero = {0.f, 0.f, 0.f, 0.f};
  #pragma unroll
  for (int i = 0; i < 2; ++i)
    #pragma unroll
    for (int n = 0; n < 7; ++n) acc[i][n] = zero;

  const u16* pa0 = outs + ((size_t)s * BATCH + wid * 32 + lr) * HID + lg * 8;
  const u16* pa1 = pa0 + 16 * HID;

  for (int kk = 0; kk < 32; ++kk){
    short8 a0 = *(const short8*)(pa0 + kk * 32);
    short8 a1 = *(const short8*)(pa1 + kk * 32);
    #pragma unroll
    for (int nt = 0; nt < 7; ++nt){
      const int j = nt * 16 + lr;
      short8 bf;
      if (j < FC1N){
        const float* wp = W1 + (size_t)j * (SEQ * HID) + (size_t)s * HID + kk * 32 + lg * 8;
        f32x4 w0 = *(const f32x4*)wp;
        f32x4 w1 = *(const f32x4*)(wp + 4);
        #pragma unroll
        for (int r = 0; r < 4; ++r){ bf[r] = (short)f2bf(w0[r]); bf[r + 4] = (short)f2bf(w1[r]); }
      } else {
        #pragma unroll
        for (int r = 0; r < 8; ++r) bf[r] = 0;
      }
      acc[0][nt] = __builtin_amdgcn_mfma_f32_16x16x32_bf16(a0, bf, acc[0][nt], 0, 0, 0);
      acc[1][nt] = __builtin_amdgcn_mfma_f32_16x16x32_bf16(a1, bf, acc[1][nt], 0, 0, 0);
    }
  }

  #pragma unroll
  for (int i = 0; i < 2; ++i)
    #pragma unroll
    for (int nt = 0; nt < 7; ++nt)
      #pragma unroll
      for (int r = 0; r < 4; ++r){
        const int b = wid * 32 + i * 16 + lg * 4 + r;
        const int j = nt * 16 + lr;
        part[((size_t)s * BATCH + b) * FC1P + j] = acc[i][nt][r];
      }
}

// ---------------- reduce partials + bias + relu + FC2 + log_softmax ----------------
__global__ __launch_bounds__(128) void reduce_kernel(const float* __restrict__ part,
                                                     const float* __restrict__ b1,
                                                     const float* __restrict__ W2,
                                                     const float* __restrict__ b2,
                                                     float* __restrict__ out){
  const int b = blockIdx.x;
  const int j = threadIdx.x;
  __shared__ float h1[FC1N];
  __shared__ float lgt[NCLS];

  if (j < FC1P){
    const float* p = part + (size_t)b * FC1P + j;
    float acc = 0.f;
    #pragma unroll 4
    for (int s = 0; s < SEQ; ++s) acc += p[(size_t)s * BATCH * FC1P];
    if (j < FC1N) h1[j] = fmaxf(acc + b1[j], 0.f);
  }
  __syncthreads();
  if (j < NCLS){
    float v = b2[j];
    for (int q = 0; q < FC1N; ++q) v += h1[q] * W2[j * FC1N + q];
    lgt[j] = v;
  }
  __syncthreads();
  if (j < NCLS){
    float m = lgt[0];
    #pragma unroll
    for (int q = 1; q < NCLS; ++q) m = fmaxf(m, lgt[q]);
    float sum = 0.f;
    #pragma unroll
    for (int q = 0; q < NCLS; ++q) sum += __expf(lgt[q] - m);
    out[b * NCLS + j] = lgt[j] - (m + __logf(sum));
  }
}

extern "C" void kernel_launch(void* const* d_in, const int* in_sizes, int n_in,
                              void* d_out, int out_size, void* d_ws, size_t ws_size,
                              hipStream_t stream){
  (void)in_sizes; (void)n_in; (void)out_size; (void)ws_size;
  const float* x   = (const float*)d_in[0];
  const float* h0  = (const float*)d_in[1];
  const float* Wih = (const float*)d_in[2];
  const float* Whh = (const float*)d_in[3];
  const float* bih = (const float*)d_in[4];
  const float* bhh = (const float*)d_in[5];
  const float* W1  = (const float*)d_in[6];
  const float* b1  = (const float*)d_in[7];
  const float* W2  = (const float*)d_in[8];
  const float* b2  = (const float*)d_in[9];
  float* out = (float*)d_out;

  char* ws = (char*)d_ws;
  int*  cnt   = (int*)(ws + OFF_SYNC);          // 8 ints
  int*  flags = (int*)(ws + OFF_SYNC + 256);    // 8*16 slots x 16-int stride
  u16*  hs    = (u16*)(ws + OFF_HS);
  u16*  whh   = (u16*)(ws + OFF_WHH);
  u16*  xp    = (u16*)(ws + OFF_XP);
  float* part = (float*)(ws + OFF_PART);

  hipMemsetAsync(ws + OFF_SYNC, 0, 16 * 1024, stream);
  cvt_f32_bf16_kernel<<<1024, 256, 0, stream>>>(Whh, whh, (HID * HID) / 4);
  cvt_f32_bf16_kernel<<<128, 256, 0, stream>>>(h0, hs, (BATCH * HID) / 4);
  xproj_kernel<<<SEQ, 1024, 0, stream>>>(x, Wih, bih, bhh, xp);
  scan_kernel<<<256, 256, 0, stream>>>(whh, xp, hs, flags, cnt);
  fc1_kernel<<<SEQ, 256, 0, stream>>>(hs + (size_t)BATCH * HID, W1, part);
  reduce_kernel<<<BATCH, 128, 0, stream>>>(part, b1, W2, b2, out);
}

// Round 5
// 1512.962 us; speedup vs baseline: 268.8233x; 268.8233x over previous
//
#include <hip/hip_runtime.h>
#include <hip/hip_bf16.h>
#include <stdint.h>
#include <stddef.h>

// tidigitsRNNPT: Elman RNN (B=128, SEQ=254, FEAT=39, HID=1024) -> FC1 -> FC2 -> log_softmax
//
// R4: sentinel-ring scan. R3 post-mortem: sub-device (sc0/SE-scope) coherence
// livelocked on stale L2 lines (432ms = 254 x full spin cap); only sc0sc1
// (IF-scope) is proven. R2's data-polling protocol was CORRECT and ~1 IF RT
// per step; it regressed only because 66MB of sentinel memset thrashed IF ->
// HBM cold misses. This round:
//  - 6-slot h ring (1.5MB, IF-resident). Team drift <=1 step => K=6 safe.
//  - per-lane re-poison of own 8B in slot (s+2)%6 at step START; the poll's
//    vmcnt(0) drain-orders poison before this step's data store (race-free).
//  - outs = separate write-only plain-store stream (off critical path).
//  - distributed poll (wave polls 8/32 frags) + LDS share, lane-linear layout
//    (lane l <-> 16B slot l: conflict-free), double-buffered -> 1 barrier/step.
//  - xp prefetched one step ahead.

typedef unsigned short u16;
typedef unsigned int u32;
typedef __attribute__((ext_vector_type(2))) unsigned int u32x2;
typedef __attribute__((ext_vector_type(4))) float f32x4;
typedef __attribute__((ext_vector_type(4))) unsigned short u16x4;
typedef __attribute__((ext_vector_type(8))) short short8;

#define SEQ   254
#define BATCH 128
#define HID   1024
#define FEAT  39
#define FC1N  100
#define FC1P  112
#define NCLS  10
#define NRING 6
#define SENT  0xAAAAAAAAu

// ---- workspace layout ----
#define OFF_RING  ((size_t)0)                                      // 6*128*1024 bf16 = 1.5MB
#define OFF_OUTS  (OFF_RING + (size_t)NRING * BATCH * HID * 2)     // 254*128*1024 bf16 = 66.6MB
#define OFF_WHH   (OFF_OUTS + (size_t)SEQ * BATCH * HID * 2)       // 2MB
#define OFF_XP    (OFF_WHH + (size_t)HID * HID * 2)                // 66.6MB
#define OFF_PART  (OFF_XP + (size_t)SEQ * BATCH * HID * 2)         // 14.6MB

__device__ inline u16 f2bf(float f){
  union { float f; unsigned u; } v; v.f = f;
  unsigned u = v.u;
  u += 0x7fffu + ((u >> 16) & 1u);
  return (u16)(u >> 16);
}
__device__ inline float bf2f(u16 h){
  union { unsigned u; float f; } v; v.u = ((unsigned)h) << 16;
  return v.f;
}
__device__ inline float fast_tanh(float x){
  // exact 0 for |x| < ~1.5e-8; smallest nonzero |out| ~5.9e-8 => bf16 0xAAAA
  // (-3.0e-13) is unproducible => safe sentinel.
  float e = __expf(2.0f * x);
  return 1.0f - 2.0f / (e + 1.0f);
}

// ---- IF-coherent (system-scope) ops: the ONLY proven cross-block medium ----
__device__ inline short8 ld_cohx4(const u16* p){
  short8 r;
  asm volatile("global_load_dwordx4 %0, %1, off sc0 sc1" : "=v"(r) : "v"(p) : "memory");
  return r;
}
__device__ inline void st_cohx2(u16* p, u32x2 v){
  asm volatile("global_store_dwordx2 %0, %1, off sc0 sc1" :: "v"(p), "v"(v) : "memory");
}

__device__ inline bool frag_bad(short8 v){
  union { short8 s; u32 w[4]; } u; u.s = v;
  return (u.w[0] == SENT) | (u.w[1] == SENT) | (u.w[2] == SENT) | (u.w[3] == SENT);
}

// ---------------- fp32 -> bf16 bulk convert ----------------
__global__ void cvt_f32_bf16_kernel(const float* __restrict__ in, u16* __restrict__ out, int n4){
  int i = blockIdx.x * blockDim.x + threadIdx.x;
  if (i < n4){
    f32x4 v = *(const f32x4*)(in + (size_t)i * 4);
    u16x4 o;
    o[0] = f2bf(v[0]); o[1] = f2bf(v[1]); o[2] = f2bf(v[2]); o[3] = f2bf(v[3]);
    *(u16x4*)(out + (size_t)i * 4) = o;
  }
}

// ---------------- xproj: [SEQ][BATCH][HID] bf16 (includes both biases) ----------------
__global__ __launch_bounds__(1024) void xproj_kernel(const float* __restrict__ x,
                                                     const float* __restrict__ W_ih,
                                                     const float* __restrict__ b_ih,
                                                     const float* __restrict__ b_hh,
                                                     u16* __restrict__ xp){
  const int s = blockIdx.x;
  __shared__ float xs[BATCH * (FEAT + 1)];
  for (int i = threadIdx.x; i < BATCH * FEAT; i += 1024){
    int b = i / FEAT, f = i - b * FEAT;
    xs[b * (FEAT + 1) + f] = x[((size_t)b * SEQ + s) * FEAT + f];
  }
  __syncthreads();
  const int h = threadIdx.x;
  float w[FEAT];
  #pragma unroll
  for (int f = 0; f < FEAT; ++f) w[f] = W_ih[h * FEAT + f];
  const float bias = b_ih[h] + b_hh[h];
  for (int b = 0; b < BATCH; ++b){
    float acc = bias;
    #pragma unroll
    for (int f = 0; f < FEAT; ++f) acc += xs[b * (FEAT + 1) + f] * w[f];
    xp[((size_t)s * BATCH + b) * HID + h] = f2bf(acc);
  }
}

// ---------------- sentinel-ring persistent RNN scan ----------------
// 128 blocks. Block (bgrp=bid&7, hgrp=bid>>3) owns h[16 b][64 h]. Per step:
// poison slot s+2 (own 8B), distributed poll slot s (wave polls 8 frags),
// LDS share, MFMA, tanh, store slot s+1 (sc0sc1) + outs (plain).
__global__ __launch_bounds__(256, 1) void scan_kernel(const u16* __restrict__ whh,
                                                      const u16* __restrict__ xp,
                                                      u16* __restrict__ ring,
                                                      u16* __restrict__ outs){
  __shared__ u16 hsh[2][32][512];     // [buf][frag kk][lane*8] : 64KB, lane-linear

  const int bid  = blockIdx.x;
  const int bgrp = bid & 7;
  const int hgrp = bid >> 3;
  const int wid  = threadIdx.x >> 6;
  const int lane = threadIdx.x & 63;
  const int lr = lane & 15;
  const int lg = lane >> 4;
  const int b_base = bgrp * 16;
  const int h_base = hgrp * 64 + wid * 16;
  const int kk0 = wid * 8;            // this wave's poll quarter

  // W_hh A-fragments, register-resident
  short8 breg[32];
  {
    const u16* wp = whh + (size_t)(h_base + lr) * HID + lg * 8;
    #pragma unroll
    for (int kk = 0; kk < 32; ++kk) breg[kk] = *(const short8*)(wp + kk * 32);
  }

  const int b_o = b_base + lr;                 // D col
  const int h_o = hgrp * 64 + wid * 16 + lg * 4;  // D rows (4 consec h)
  const size_t poll_off = (size_t)(b_base + lr) * HID + lg * 8;
  const size_t st_off   = (size_t)b_o * HID + h_o;

  const u32x2 sent2 = {SENT, SENT};

  // prologue: xv for s=0
  u16x4 xv = *(const u16x4*)(xp + (size_t)b_o * HID + h_o);

  for (int s = 0; s < SEQ; ++s){
    // 1) poison own 8B in slot s+2 (drain-ordered before this step's data store)
    st_cohx2(ring + (size_t)((s + 2) % NRING) * (BATCH * HID) + st_off, sent2);

    // 2) distributed poll of slot s (this wave's 8 fragments)
    const u16* pp = ring + (size_t)(s % NRING) * (BATCH * HID) + poll_off;
    short8 f[8];
    u32 bad = 0xFFu;
    while (bad){
      #pragma unroll
      for (int i = 0; i < 8; ++i)
        if (bad & (1u << i)) f[i] = ld_cohx4(pp + (kk0 + i) * 32);
      asm volatile("s_waitcnt vmcnt(0)" ::: "memory");
      __builtin_amdgcn_sched_barrier(0);
      u32 nb = 0;
      #pragma unroll
      for (int i = 0; i < 8; ++i)
        if (bad & (1u << i)) nb |= (__ballot(frag_bad(f[i])) != 0ull) ? (1u << i) : 0u;
      bad = nb;
    }

    // 3) share via LDS (lane-linear: conflict-free), double-buffered
    u16* wb = &hsh[s & 1][0][0];
    #pragma unroll
    for (int i = 0; i < 8; ++i)
      *(short8*)(wb + (size_t)(kk0 + i) * 512 + lane * 8) = f[i];

    // prefetch xp for next step (plain cached; drained by next poll)
    u16x4 xv_next;
    if (s + 1 < SEQ)
      xv_next = *(const u16x4*)(xp + ((size_t)(s + 1) * BATCH + b_o) * HID + h_o);

    __syncthreads();

    // 4) MFMA over all 32 fragments from LDS
    f32x4 acc0, acc1 = {0.f, 0.f, 0.f, 0.f};
    acc0[0] = bf2f(xv[0]); acc0[1] = bf2f(xv[1]); acc0[2] = bf2f(xv[2]); acc0[3] = bf2f(xv[3]);
    #pragma unroll
    for (int kk = 0; kk < 32; kk += 2){
      short8 a0 = *(const short8*)(wb + (size_t)kk * 512 + lane * 8);
      short8 a1 = *(const short8*)(wb + (size_t)(kk + 1) * 512 + lane * 8);
      acc0 = __builtin_amdgcn_mfma_f32_16x16x32_bf16(breg[kk],     a0, acc0, 0, 0, 0);
      acc1 = __builtin_amdgcn_mfma_f32_16x16x32_bf16(breg[kk + 1], a1, acc1, 0, 0, 0);
    }

    // 5) tanh -> pack -> ring store (coherent) + outs store (plain)
    u32x2 d;
    {
      float v0 = fast_tanh(acc0[0] + acc1[0]);
      float v1 = fast_tanh(acc0[1] + acc1[1]);
      float v2 = fast_tanh(acc0[2] + acc1[2]);
      float v3 = fast_tanh(acc0[3] + acc1[3]);
      d[0] = (u32)f2bf(v0) | ((u32)f2bf(v1) << 16);
      d[1] = (u32)f2bf(v2) | ((u32)f2bf(v3) << 16);
    }
    st_cohx2(ring + (size_t)((s + 1) % NRING) * (BATCH * HID) + st_off, d);
    *(u32x2*)(outs + ((size_t)s * BATCH + b_o) * HID + h_o) = d;

    xv = xv_next;
  }
}

// ---------------- FC1 partials via MFMA ----------------
__global__ __launch_bounds__(256) void fc1_kernel(const u16* __restrict__ outs,
                                                  const float* __restrict__ W1,
                                                  float* __restrict__ part){
  const int s = blockIdx.x;
  const int wid  = threadIdx.x >> 6;
  const int lane = threadIdx.x & 63;
  const int lr = lane & 15;
  const int lg = lane >> 4;

  f32x4 acc[2][7];
  const f32x4 zero = {0.f, 0.f, 0.f, 0.f};
  #pragma unroll
  for (int i = 0; i < 2; ++i)
    #pragma unroll
    for (int n = 0; n < 7; ++n) acc[i][n] = zero;

  const u16* pa0 = outs + ((size_t)s * BATCH + wid * 32 + lr) * HID + lg * 8;
  const u16* pa1 = pa0 + 16 * HID;

  for (int kk = 0; kk < 32; ++kk){
    short8 a0 = *(const short8*)(pa0 + kk * 32);
    short8 a1 = *(const short8*)(pa1 + kk * 32);
    #pragma unroll
    for (int nt = 0; nt < 7; ++nt){
      const int j = nt * 16 + lr;
      short8 bf;
      if (j < FC1N){
        const float* wp = W1 + (size_t)j * (SEQ * HID) + (size_t)s * HID + kk * 32 + lg * 8;
        f32x4 w0 = *(const f32x4*)wp;
        f32x4 w1 = *(const f32x4*)(wp + 4);
        #pragma unroll
        for (int r = 0; r < 4; ++r){ bf[r] = (short)f2bf(w0[r]); bf[r + 4] = (short)f2bf(w1[r]); }
      } else {
        #pragma unroll
        for (int r = 0; r < 8; ++r) bf[r] = 0;
      }
      acc[0][nt] = __builtin_amdgcn_mfma_f32_16x16x32_bf16(a0, bf, acc[0][nt], 0, 0, 0);
      acc[1][nt] = __builtin_amdgcn_mfma_f32_16x16x32_bf16(a1, bf, acc[1][nt], 0, 0, 0);
    }
  }

  #pragma unroll
  for (int i = 0; i < 2; ++i)
    #pragma unroll
    for (int nt = 0; nt < 7; ++nt)
      #pragma unroll
      for (int r = 0; r < 4; ++r){
        const int b = wid * 32 + i * 16 + lg * 4 + r;
        const int j = nt * 16 + lr;
        part[((size_t)s * BATCH + b) * FC1P + j] = acc[i][nt][r];
      }
}

// ---------------- reduce partials + bias + relu + FC2 + log_softmax ----------------
__global__ __launch_bounds__(128) void reduce_kernel(const float* __restrict__ part,
                                                     const float* __restrict__ b1,
                                                     const float* __restrict__ W2,
                                                     const float* __restrict__ b2,
                                                     float* __restrict__ out){
  const int b = blockIdx.x;
  const int j = threadIdx.x;
  __shared__ float h1[FC1N];
  __shared__ float lgt[NCLS];

  if (j < FC1P){
    const float* p = part + (size_t)b * FC1P + j;
    float acc = 0.f;
    #pragma unroll 4
    for (int s = 0; s < SEQ; ++s) acc += p[(size_t)s * BATCH * FC1P];
    if (j < FC1N) h1[j] = fmaxf(acc + b1[j], 0.f);
  }
  __syncthreads();
  if (j < NCLS){
    float v = b2[j];
    for (int q = 0; q < FC1N; ++q) v += h1[q] * W2[j * FC1N + q];
    lgt[j] = v;
  }
  __syncthreads();
  if (j < NCLS){
    float m = lgt[0];
    #pragma unroll
    for (int q = 1; q < NCLS; ++q) m = fmaxf(m, lgt[q]);
    float sum = 0.f;
    #pragma unroll
    for (int q = 0; q < NCLS; ++q) sum += __expf(lgt[q] - m);
    out[b * NCLS + j] = lgt[j] - (m + __logf(sum));
  }
}

extern "C" void kernel_launch(void* const* d_in, const int* in_sizes, int n_in,
                              void* d_out, int out_size, void* d_ws, size_t ws_size,
                              hipStream_t stream){
  (void)in_sizes; (void)n_in; (void)out_size; (void)ws_size;
  const float* x   = (const float*)d_in[0];
  const float* h0  = (const float*)d_in[1];
  const float* Wih = (const float*)d_in[2];
  const float* Whh = (const float*)d_in[3];
  const float* bih = (const float*)d_in[4];
  const float* bhh = (const float*)d_in[5];
  const float* W1  = (const float*)d_in[6];
  const float* b1  = (const float*)d_in[7];
  const float* W2  = (const float*)d_in[8];
  const float* b2  = (const float*)d_in[9];
  float* out = (float*)d_out;

  char* ws = (char*)d_ws;
  u16*  ring = (u16*)(ws + OFF_RING);
  u16*  outs = (u16*)(ws + OFF_OUTS);
  u16*  whh  = (u16*)(ws + OFF_WHH);
  u16*  xp   = (u16*)(ws + OFF_XP);
  float* part = (float*)(ws + OFF_PART);

  // poison ring slots 1..5 (slot 0 = h0); tiny (1.28MB), stays cache-resident
  hipMemsetAsync(ring + (size_t)BATCH * HID, 0xAA, (size_t)(NRING - 1) * BATCH * HID * 2, stream);
  cvt_f32_bf16_kernel<<<1024, 256, 0, stream>>>(Whh, whh, (HID * HID) / 4);
  cvt_f32_bf16_kernel<<<128, 256, 0, stream>>>(h0, ring, (BATCH * HID) / 4);
  xproj_kernel<<<SEQ, 1024, 0, stream>>>(x, Wih, bih, bhh, xp);
  scan_kernel<<<128, 256, 0, stream>>>(whh, xp, ring, outs);
  fc1_kernel<<<SEQ, 256, 0, stream>>>(outs, W1, part);
  reduce_kernel<<<BATCH, 128, 0, stream>>>(part, b1, W2, b2, out);
}